// Round 3
// baseline (186.626 us; speedup 1.0000x reference)
//
#include <hip/hip_runtime.h>
#include <math.h>

#define SS 4096
#define EE 1024
#define HH 16
#define DD 64
#define LP 256    // max supported segment length
#define ROWS 256

// ---------------------------------------------------------------------------
// ws layout:
//   ints[0..1]            : meta (s0, L)
//   floats 64..+E         : sumx[E]
//   floats ..+E           : bg[E]
//   floats ..+E           : mwv[E]  (atomic SUM of wv rows)
//   byte 16384            : qb [ROWS][E]   (atomic-accumulated; becomes wv)
//   + ROWS*E floats       : kb [ROWS][E]
//   + ROWS*E floats       : vb [ROWS][E]
//   + ROWS*E floats       : kt [E][LP]
// First 16384 + 3*ROWS*E*4 bytes are zeroed by hipMemsetAsync each call.
// ---------------------------------------------------------------------------

// sumx (column sum of x) + segment-range scan fused. grid (4,64), block 256.
__global__ void prep_kernel(const float* __restrict__ x,
                            const int* __restrict__ seg, const int* __restrict__ posp,
                            float* __restrict__ sumx, int* __restrict__ meta) {
    int e  = blockIdx.x * 256 + threadIdx.x;
    int r0 = blockIdx.y * (SS / 64);
    float a = 0.f;
    for (int r = r0; r < r0 + SS / 64; ++r) a += x[(size_t)r * EE + e];
    atomicAdd(&sumx[e], a);

    if (blockIdx.x == 0 && blockIdx.y == 0) {
        __shared__ int smin, smax;
        if (threadIdx.x == 0) { smin = SS; smax = -1; }
        __syncthreads();
        int sid = seg[posp[0]];
        int lmin = SS, lmax = -1;
        for (int i = threadIdx.x; i < SS; i += 256) {
            if (seg[i] == sid) { lmin = min(lmin, i); lmax = max(lmax, i); }
        }
        atomicMin(&smin, lmin);
        atomicMax(&smax, lmax);
        __syncthreads();
        if (threadIdx.x == 0) {
            int L = smax - smin + 1;
            if (L > LP) L = LP;   // safety clamp
            meta[0] = smin;
            meta[1] = L;
        }
    }
}

// Skinny GEMM projections: y[r][e] = sum_k x[s0+r][k]*W[e][k] (+ bias at kc==0).
// Block: one (matrix m, 32-col e-tile, 128-wide K-chunk, 64-row block).
// lane = row. xs[k][r] per-lane reads; ws[k][e] wave-uniform broadcast reads.
__global__ __launch_bounds__(256) void proj_kernel(
    const float* __restrict__ x,
    const float* __restrict__ Wq, const float* __restrict__ bq,
    const float* __restrict__ Wk, const float* __restrict__ bk,
    const float* __restrict__ Wv, const float* __restrict__ bv,
    const int* __restrict__ meta,
    float* __restrict__ qb, float* __restrict__ kb, float* __restrict__ vb) {
    __shared__ float lds[128 * 65 + 128 * 36];
    int s0 = meta[0], L = meta[1];
    int r0 = blockIdx.y * 64;
    if (r0 >= L) return;
    int bid = blockIdx.x;
    int m   = bid >> 8;          // 0..2
    int rem = bid & 255;
    int kc  = rem >> 5;          // 0..7  (consecutive bids share x K-chunk)
    int et  = rem & 31;          // 0..31 (32-col tile)
    const float* W = (m == 0) ? Wq : ((m == 1) ? Wk : Wv);
    const float* b = (m == 0) ? bq : ((m == 1) ? bk : bv);
    float*       y = (m == 0) ? qb : ((m == 1) ? kb : vb);
    int k0  = kc * 128;
    int tid = threadIdx.x;
    float* xs = lds;             // [128][65]
    float* ws = lds + 128 * 65;  // [128][36]

    for (int idx = tid; idx < 64 * 128; idx += 256) {
        int k = idx & 127, r = idx >> 7;
        float v = (r0 + r < L) ? x[(size_t)(s0 + r0 + r) * EE + k0 + k] : 0.f;
        xs[k * 65 + r] = v;
    }
    for (int idx = tid; idx < 32 * 128; idx += 256) {
        int k = idx & 127, e = idx >> 7;
        ws[k * 36 + e] = W[(size_t)(et * 32 + e) * EE + k0 + k];
    }
    __syncthreads();

    int lane = tid & 63, wave = tid >> 6;
    int eo = wave << 3;
    float acc[8] = {0.f, 0.f, 0.f, 0.f, 0.f, 0.f, 0.f, 0.f};
#pragma unroll 4
    for (int k = 0; k < 128; ++k) {
        float xr = xs[k * 65 + lane];
        const float4* wp = (const float4*)&ws[k * 36 + eo];
        float4 w0 = wp[0];
        float4 w1 = wp[1];
        acc[0] += w0.x * xr; acc[1] += w0.y * xr;
        acc[2] += w0.z * xr; acc[3] += w0.w * xr;
        acc[4] += w1.x * xr; acc[5] += w1.y * xr;
        acc[6] += w1.z * xr; acc[7] += w1.w * xr;
    }
    int rg = r0 + lane;
    if (rg < L) {
        int eb = et * 32 + eo;
#pragma unroll
        for (int j = 0; j < 8; ++j) {
            float add = acc[j] + ((kc == 0) ? b[eb + j] : 0.f);
            atomicAdd(&y[(size_t)rg * EE + eb + j], add);
        }
    }
}

// kt[e][t] = kb[t][e], LDS-tiled transpose. grid (LP/64,16), block 256.
__global__ void kt_kernel(const int* __restrict__ meta, const float* __restrict__ kb,
                          float* __restrict__ kt) {
    __shared__ float tile[64][65];
    int L = meta[1];
    int t0 = blockIdx.x * 64;
    if (t0 >= L) return;
    int e0 = blockIdx.y * 64;
    int tid = threadIdx.x;
    for (int idx = tid; idx < 4096; idx += 256) {
        int tr = idx >> 6, ec = idx & 63;
        tile[tr][ec] = kb[(size_t)(t0 + tr) * EE + e0 + ec];
    }
    __syncthreads();
    for (int idx = tid; idx < 4096; idx += 256) {
        int d = idx >> 6, tl = idx & 63;
        kt[(size_t)(e0 + d) * LP + t0 + tl] = tile[tl][d];
    }
}

// bg[e] = S*bv[e] + (Wv . sumx)[e] - sum_{t<L} vb[t][e].  One wave per e.
__global__ __launch_bounds__(256) void bg_kernel(
    const int* __restrict__ meta, const float* __restrict__ Wv,
    const float* __restrict__ bv, const float* __restrict__ sumx,
    const float* __restrict__ vb, float* __restrict__ bg) {
    int L = meta[1];
    int gid  = blockIdx.x * 256 + threadIdx.x;
    int e    = gid >> 6;
    int lane = gid & 63;
    float p = 0.f;
    const float* wr = Wv + (size_t)e * EE;
    for (int j0 = 0; j0 < EE; j0 += 64) p += wr[j0 + lane] * sumx[j0 + lane];
    for (int t = lane; t < L; t += 64) p -= vb[(size_t)t * EE + e];
#pragma unroll
    for (int off = 32; off; off >>= 1) p += __shfl_xor(p, off);
    if (lane == 0) bg[e] = p + (float)SS * bv[e];
}

// attention: one wave per (segment-row, head). lane=t for scores, lane=d for PV.
__global__ __launch_bounds__(64) void attn_kernel(
    const int* __restrict__ meta, float* __restrict__ qb,
    const float* __restrict__ kt, const float* __restrict__ vb,
    const float* __restrict__ bg) {
    __shared__ float sc[LP / 64][64];
    int L = meta[1];
    int lane = threadIdx.x;
    int nt = (L + 63) >> 6;
    int total = L * HH;
    for (int it = blockIdx.x; it < total; it += gridDim.x) {
        int h  = it & (HH - 1);
        int sl = it >> 4;
        float qreg = qb[(size_t)sl * EE + h * DD + lane];
        const float* kth = kt + (size_t)(h * DD) * LP;
        float mmax = (L < SS) ? 0.f : -3.0e38f;
        for (int t0 = 0; t0 < nt; ++t0) {
            float s = 0.f;
            const float* kp = kth + t0 * 64 + lane;
#pragma unroll
            for (int d = 0; d < 64; ++d) {
                float qd = __shfl(qreg, d);
                s += qd * kp[(size_t)d * LP];
            }
            sc[t0][lane] = s;
            bool valid = (t0 * 64 + lane) < L;
            mmax = fmaxf(mmax, valid ? s : -3.0e38f);
        }
#pragma unroll
        for (int off = 32; off; off >>= 1) mmax = fmaxf(mmax, __shfl_xor(mmax, off));
        float Zl = 0.f;
        for (int t0 = 0; t0 < nt; ++t0) {
            bool valid = (t0 * 64 + lane) < L;
            float w = valid ? __expf(sc[t0][lane] - mmax) : 0.f;
            Zl += w;
            sc[t0][lane] = w;
        }
#pragma unroll
        for (int off = 32; off; off >>= 1) Zl += __shfl_xor(Zl, off);
        float Z = Zl + (float)(SS - L) * __expf(-mmax);
        __syncthreads();
        float acc = 0.f;
        for (int t0 = 0; t0 < nt; ++t0) {
            const float* vp = vb + (size_t)(t0 * 64) * EE + h * DD + lane;
#pragma unroll
            for (int tt = 0; tt < 64; ++tt) acc += sc[t0][tt] * vp[(size_t)tt * EE];
        }
        float o = (acc + __expf(-mmax) * bg[h * DD + lane]) / Z;
        __syncthreads();
        qb[(size_t)sl * EE + h * DD + lane] = o;   // qb becomes wv
    }
}

// mwv[e] += partial sums of wv rows (division by L folded into out_kernel)
__global__ void mean_kernel(const int* __restrict__ meta, const float* __restrict__ wv,
                            float* __restrict__ mwv) {
    int L = meta[1];
    int e = blockIdx.x * 256 + threadIdx.x;
    int tc = blockIdx.y;
    float a = 0.f;
    for (int t = tc; t < L; t += 16) a += wv[(size_t)t * EE + e];
    atomicAdd(&mwv[e], a);
}

// out[e] = (mwv . Wo[e,:]) / L + bo[e]; one wave per output element
__global__ __launch_bounds__(256) void out_kernel(
    const int* __restrict__ meta, const float* __restrict__ mwv,
    const float* __restrict__ Wo, const float* __restrict__ bo,
    float* __restrict__ out) {
    int L = meta[1];
    int gid  = blockIdx.x * 256 + threadIdx.x;
    int e    = gid >> 6;
    int lane = gid & 63;
    float a = 0.f;
    const float* wrow = Wo + (size_t)e * EE;
    for (int j0 = 0; j0 < EE; j0 += 64) a += mwv[j0 + lane] * wrow[j0 + lane];
#pragma unroll
    for (int off = 32; off; off >>= 1) a += __shfl_xor(a, off);
    if (lane == 0) out[e] = a / (float)L + bo[e];
}

extern "C" void kernel_launch(void* const* d_in, const int* in_sizes, int n_in,
                              void* d_out, int out_size, void* d_ws, size_t ws_size,
                              hipStream_t stream) {
    const float* x   = (const float*)d_in[0];
    const float* Wq  = (const float*)d_in[1];
    const float* bq  = (const float*)d_in[2];
    const float* Wk  = (const float*)d_in[3];
    const float* bk  = (const float*)d_in[4];
    const float* Wv  = (const float*)d_in[5];
    const float* bv  = (const float*)d_in[6];
    const float* Wo  = (const float*)d_in[7];
    const float* bo  = (const float*)d_in[8];
    const int*   seg = (const int*)d_in[9];
    const int*   pos = (const int*)d_in[10];
    float*       out = (float*)d_out;

    int*   meta = (int*)d_ws;
    float* fws  = (float*)d_ws;
    float* sumx = fws + 64;
    float* bg   = fws + 64 + EE;
    float* mwv  = fws + 64 + 2 * EE;

    size_t rowbytes = (size_t)ROWS * EE * sizeof(float);
    float* qb = (float*)((char*)d_ws + 16384);
    float* kb = qb + (size_t)ROWS * EE;
    float* vb = kb + (size_t)ROWS * EE;
    float* kt = vb + (size_t)ROWS * EE;

    // zero header (meta/sumx/bg/mwv) + qb/kb/vb (atomic accumulators)
    hipMemsetAsync(d_ws, 0, 16384 + 3 * rowbytes, stream);

    prep_kernel<<<dim3(4, 64), 256, 0, stream>>>(x, seg, pos, sumx, meta);
    proj_kernel<<<dim3(768, ROWS / 64), 256, 0, stream>>>(x, Wq, bq, Wk, bk, Wv, bv,
                                                          meta, qb, kb, vb);
    kt_kernel<<<dim3(LP / 64, 16), 256, 0, stream>>>(meta, kb, kt);
    bg_kernel<<<256, 256, 0, stream>>>(meta, Wv, bv, sumx, vb, bg);
    attn_kernel<<<1024, 64, 0, stream>>>(meta, qb, kt, vb, bg);
    mean_kernel<<<dim3(4, 16), 256, 0, stream>>>(meta, qb, mwv);
    out_kernel<<<256, 256, 0, stream>>>(meta, mwv, Wo, bo, out);
}

// Round 4
// 90.711 us; speedup vs baseline: 2.0574x; 2.0574x over previous
//
#include <hip/hip_runtime.h>
#include <math.h>

#define SS 4096
#define EE 1024
#define HH 16
#define DD 64
#define RMAX 128   // max supported segment length (mean 64, sigma ~8)

// ---------------------------------------------------------------------------
// ws layout:
//   ints[0..1]        : meta (s0, L)
//   floats 64..+E     : sumx[E]
//   floats ..+E       : bg[E]
//   floats ..+E       : mwv[E]  (atomic SUM of wv rows; /L folded into out)
//   byte 16384        : qb [RMAX][E]
//   +RMAX*E           : kb [RMAX][E]
//   +RMAX*E           : vb [RMAX][E]
//   +RMAX*E           : kt [E][RMAX]
//   +RMAX*E           : part [256][E]          (x column-sum partials)
//   +256*E            : ypart [12][RMAX][E]    (proj K-chunk partials, 6 MB)
// Only the first 16384 bytes are memset to 0 each call.
// ---------------------------------------------------------------------------

// x column-sum partials (blocks 0..255, 16 rows each) + segment scan (block 256)
__global__ __launch_bounds__(256) void colsum_kernel(
    const float* __restrict__ x, const int* __restrict__ seg,
    const int* __restrict__ posp, float* __restrict__ part, int* __restrict__ meta) {
    if (blockIdx.x == 256) {
        __shared__ int smin, smax;
        if (threadIdx.x == 0) { smin = SS; smax = -1; }
        __syncthreads();
        int sid = seg[posp[0]];
        int lmin = SS, lmax = -1;
        for (int i = threadIdx.x; i < SS; i += 256)
            if (seg[i] == sid) { lmin = min(lmin, i); lmax = max(lmax, i); }
        atomicMin(&smin, lmin);
        atomicMax(&smax, lmax);
        __syncthreads();
        if (threadIdx.x == 0) {
            int L = smax - smin + 1;
            if (L > RMAX) L = RMAX;
            meta[0] = smin;
            meta[1] = L;
        }
        return;
    }
    int r0 = blockIdx.x * 16;
    int c  = threadIdx.x;                       // float4 column
    const float4* x4 = (const float4*)x;
    float4 a = make_float4(0.f, 0.f, 0.f, 0.f);
#pragma unroll 4
    for (int r = r0; r < r0 + 16; ++r) {
        float4 v = x4[(size_t)r * 256 + c];
        a.x += v.x; a.y += v.y; a.z += v.z; a.w += v.w;
    }
    ((float4*)part)[(size_t)blockIdx.x * 256 + c] = a;
}

// part[256][E] -> sumx[E], 16-way atomic. grid (4,16), block 256.
__global__ void sumxr_kernel(const float* __restrict__ part, float* __restrict__ sumx) {
    int e  = blockIdx.x * 256 + threadIdx.x;
    int c0 = blockIdx.y * 16;
    float s = 0.f;
#pragma unroll
    for (int c = 0; c < 16; ++c) s += part[(size_t)(c0 + c) * EE + e];
    atomicAdd(&sumx[e], s);
}

// Projections, partial over K. Block = (m, kc in 0..3, et in 0..31) x rowblock.
// Each block loops 2 x 128-wide K staging rounds, register-accumulated,
// then plain float4 stores to ypart slab (m*4+kc).
__global__ __launch_bounds__(256) void proj_kernel(
    const float* __restrict__ x,
    const float* __restrict__ Wq, const float* __restrict__ Wk,
    const float* __restrict__ Wv,
    const int* __restrict__ meta, float* __restrict__ ypart) {
    __shared__ float xs[128 * 65];   // [k][r]
    __shared__ float wsm[128 * 36];  // [k][e]
    int s0 = meta[0], L = meta[1];
    int r0 = blockIdx.y * 64;
    if (r0 >= L) return;
    int bid = blockIdx.x;
    int m   = bid >> 7;
    int rem = bid & 127;
    int kc  = rem >> 5;
    int et  = rem & 31;
    const float* W = (m == 0) ? Wq : ((m == 1) ? Wk : Wv);
    int tid = threadIdx.x, lane = tid & 63, wave = tid >> 6;
    int eo = wave << 3;
    float acc[8] = {0.f, 0.f, 0.f, 0.f, 0.f, 0.f, 0.f, 0.f};
    for (int rr = 0; rr < 2; ++rr) {
        int k0 = kc * 256 + rr * 128;
        __syncthreads();
        for (int idx = tid; idx < 2048; idx += 256) {   // xs: 64r x 32 k4
            int k4 = idx & 31, r = idx >> 5;
            float4 v = make_float4(0.f, 0.f, 0.f, 0.f);
            if (r0 + r < L)
                v = *(const float4*)(x + (size_t)(s0 + r0 + r) * EE + k0 + k4 * 4);
            xs[(k4 * 4 + 0) * 65 + r] = v.x;
            xs[(k4 * 4 + 1) * 65 + r] = v.y;
            xs[(k4 * 4 + 2) * 65 + r] = v.z;
            xs[(k4 * 4 + 3) * 65 + r] = v.w;
        }
        for (int idx = tid; idx < 1024; idx += 256) {   // ws: 32e x 32 k4
            int k4 = idx & 31, e = idx >> 5;
            float4 v = *(const float4*)(W + (size_t)(et * 32 + e) * EE + k0 + k4 * 4);
            wsm[(k4 * 4 + 0) * 36 + e] = v.x;
            wsm[(k4 * 4 + 1) * 36 + e] = v.y;
            wsm[(k4 * 4 + 2) * 36 + e] = v.z;
            wsm[(k4 * 4 + 3) * 36 + e] = v.w;
        }
        __syncthreads();
#pragma unroll 4
        for (int k = 0; k < 128; ++k) {
            float xr = xs[k * 65 + lane];
            const float4* wp = (const float4*)&wsm[k * 36 + eo];
            float4 w0 = wp[0], w1 = wp[1];
            acc[0] += w0.x * xr; acc[1] += w0.y * xr;
            acc[2] += w0.z * xr; acc[3] += w0.w * xr;
            acc[4] += w1.x * xr; acc[5] += w1.y * xr;
            acc[6] += w1.z * xr; acc[7] += w1.w * xr;
        }
    }
    float* dst = ypart + ((size_t)(m * 4 + kc) * RMAX + (r0 + lane)) * EE + et * 32 + eo;
    *(float4*)dst       = make_float4(acc[0], acc[1], acc[2], acc[3]);
    *(float4*)(dst + 4) = make_float4(acc[4], acc[5], acc[6], acc[7]);
}

// qb/kb/vb[r][e] = sum of 4 ypart slabs + bias. grid (3, RMAX), block 256.
__global__ void projred_kernel(
    const int* __restrict__ meta, const float* __restrict__ ypart,
    const float* __restrict__ bq, const float* __restrict__ bk,
    const float* __restrict__ bv,
    float* __restrict__ qb, float* __restrict__ kb, float* __restrict__ vb) {
    int L = meta[1];
    int r = blockIdx.y;
    if (r >= L) return;
    int m = blockIdx.x;
    int c = threadIdx.x;
    const size_t slab = (size_t)RMAX * 256;   // in float4 units
    const float4* yp = (const float4*)ypart + ((size_t)(m * 4) * RMAX + r) * 256;
    float4 s0 = yp[c], s1 = yp[slab + c], s2 = yp[2 * slab + c], s3 = yp[3 * slab + c];
    const float* b = (m == 0) ? bq : ((m == 1) ? bk : bv);
    float4 bb = ((const float4*)b)[c];
    float4 o = make_float4(s0.x + s1.x + s2.x + s3.x + bb.x,
                           s0.y + s1.y + s2.y + s3.y + bb.y,
                           s0.z + s1.z + s2.z + s3.z + bb.z,
                           s0.w + s1.w + s2.w + s3.w + bb.w);
    float* y = (m == 0) ? qb : ((m == 1) ? kb : vb);
    ((float4*)(y + (size_t)r * EE))[c] = o;
}

// kt[e][t] = kb[t][e]. grid (RMAX/64, 16), block 256.
__global__ void kt_kernel(const float* __restrict__ kb, float* __restrict__ kt) {
    __shared__ float tile[64][65];
    int t0 = blockIdx.x * 64;
    int e0 = blockIdx.y * 64;
    int tid = threadIdx.x;
    for (int idx = tid; idx < 4096; idx += 256) {
        int tr = idx >> 6, ec = idx & 63;
        tile[tr][ec] = kb[(size_t)(t0 + tr) * EE + e0 + ec];
    }
    __syncthreads();
    for (int idx = tid; idx < 4096; idx += 256) {
        int d = idx >> 6, tl = idx & 63;
        kt[(size_t)(e0 + d) * RMAX + t0 + tl] = tile[tl][d];
    }
}

// bg[e] = S*bv[e] + (Wv . sumx)[e] - sum_{t<L} vb[t][e].  One wave per e.
__global__ __launch_bounds__(256) void bg_kernel(
    const int* __restrict__ meta, const float* __restrict__ Wv,
    const float* __restrict__ bv, const float* __restrict__ sumx,
    const float* __restrict__ vb, float* __restrict__ bg) {
    int L = meta[1];
    int gid  = blockIdx.x * 256 + threadIdx.x;
    int e    = gid >> 6;
    int lane = gid & 63;
    const float4* w4 = (const float4*)(Wv + (size_t)e * EE);
    const float4* s4 = (const float4*)sumx;
    float p = 0.f;
#pragma unroll
    for (int j = 0; j < 4; ++j) {
        float4 w = w4[j * 64 + lane], s = s4[j * 64 + lane];
        p += w.x * s.x + w.y * s.y + w.z * s.z + w.w * s.w;
    }
    for (int t = lane; t < L; t += 64) p -= vb[(size_t)t * EE + e];
#pragma unroll
    for (int off = 32; off; off >>= 1) p += __shfl_xor(p, off);
    if (lane == 0) bg[e] = p + (float)SS * bv[e];
}

// attention: one wave per (segment-row, head); accumulates row mean into mwv.
__global__ __launch_bounds__(64) void attn_kernel(
    const int* __restrict__ meta, const float* __restrict__ qb,
    const float* __restrict__ kt, const float* __restrict__ vb,
    const float* __restrict__ bg, float* __restrict__ mwv) {
    __shared__ float sc[RMAX / 64][64];
    int L = meta[1];
    int lane = threadIdx.x;
    int nt = (L + 63) >> 6;
    int total = L * HH;
    for (int it = blockIdx.x; it < total; it += gridDim.x) {
        int h  = it & (HH - 1);
        int sl = it >> 4;
        float qreg = qb[(size_t)sl * EE + h * DD + lane];
        const float* kth = kt + (size_t)(h * DD) * RMAX;
        float mmax = 0.f;   // L < SS always, zero background participates
        for (int t0 = 0; t0 < nt; ++t0) {
            float s = 0.f;
            const float* kp = kth + t0 * 64 + lane;
#pragma unroll
            for (int d = 0; d < 64; ++d) s += __shfl(qreg, d) * kp[(size_t)d * RMAX];
            sc[t0][lane] = s;
            mmax = fmaxf(mmax, (t0 * 64 + lane < L) ? s : -3.0e38f);
        }
#pragma unroll
        for (int off = 32; off; off >>= 1) mmax = fmaxf(mmax, __shfl_xor(mmax, off));
        float Zl = 0.f;
        for (int t0 = 0; t0 < nt; ++t0) {
            float w = (t0 * 64 + lane < L) ? __expf(sc[t0][lane] - mmax) : 0.f;
            Zl += w;
            sc[t0][lane] = w;
        }
#pragma unroll
        for (int off = 32; off; off >>= 1) Zl += __shfl_xor(Zl, off);
        float Z = Zl + (float)(SS - L) * __expf(-mmax);
        float acc = 0.f;
        for (int t0 = 0; t0 < nt; ++t0) {
            const float* vp = vb + (size_t)(t0 * 64) * EE + h * DD + lane;
            int lim = min(64, L - t0 * 64);
            for (int tt = 0; tt < lim; ++tt) acc += sc[t0][tt] * vp[(size_t)tt * EE];
        }
        float o = (acc + __expf(-mmax) * bg[h * DD + lane]) / Z;
        atomicAdd(&mwv[h * DD + lane], o);
    }
}

// out[e] = (mwv . Wo[e,:]) / L + bo[e]; one wave per output element
__global__ __launch_bounds__(256) void out_kernel(
    const int* __restrict__ meta, const float* __restrict__ mwv,
    const float* __restrict__ Wo, const float* __restrict__ bo,
    float* __restrict__ out) {
    int L = meta[1];
    int gid  = blockIdx.x * 256 + threadIdx.x;
    int e    = gid >> 6;
    int lane = gid & 63;
    const float4* w4 = (const float4*)(Wo + (size_t)e * EE);
    const float4* m4 = (const float4*)mwv;
    float a = 0.f;
#pragma unroll
    for (int j = 0; j < 4; ++j) {
        float4 w = w4[j * 64 + lane], mm = m4[j * 64 + lane];
        a += w.x * mm.x + w.y * mm.y + w.z * mm.z + w.w * mm.w;
    }
#pragma unroll
    for (int off = 32; off; off >>= 1) a += __shfl_xor(a, off);
    if (lane == 0) out[e] = a / (float)L + bo[e];
}

extern "C" void kernel_launch(void* const* d_in, const int* in_sizes, int n_in,
                              void* d_out, int out_size, void* d_ws, size_t ws_size,
                              hipStream_t stream) {
    const float* x   = (const float*)d_in[0];
    const float* Wq  = (const float*)d_in[1];
    const float* bq  = (const float*)d_in[2];
    const float* Wk  = (const float*)d_in[3];
    const float* bk  = (const float*)d_in[4];
    const float* Wv  = (const float*)d_in[5];
    const float* bv  = (const float*)d_in[6];
    const float* Wo  = (const float*)d_in[7];
    const float* bo  = (const float*)d_in[8];
    const int*   seg = (const int*)d_in[9];
    const int*   pos = (const int*)d_in[10];
    float*       out = (float*)d_out;

    int*   meta = (int*)d_ws;
    float* fws  = (float*)d_ws;
    float* sumx = fws + 64;
    float* bg   = fws + 64 + EE;
    float* mwv  = fws + 64 + 2 * EE;
    float* qb   = (float*)((char*)d_ws + 16384);
    float* kb   = qb + (size_t)RMAX * EE;
    float* vb   = kb + (size_t)RMAX * EE;
    float* kt   = vb + (size_t)RMAX * EE;
    float* part = kt + (size_t)RMAX * EE;
    float* ypart = part + (size_t)256 * EE;

    hipMemsetAsync(d_ws, 0, 16384, stream);

    colsum_kernel<<<257, 256, 0, stream>>>(x, seg, pos, part, meta);
    sumxr_kernel<<<dim3(4, 16), 256, 0, stream>>>(part, sumx);
    proj_kernel<<<dim3(384, RMAX / 64), 256, 0, stream>>>(x, Wq, Wk, Wv, meta, ypart);
    projred_kernel<<<dim3(3, RMAX), 256, 0, stream>>>(meta, ypart, bq, bk, bv, qb, kb, vb);
    kt_kernel<<<dim3(RMAX / 64, 16), 256, 0, stream>>>(kb, kt);
    bg_kernel<<<256, 256, 0, stream>>>(meta, Wv, bv, sumx, vb, bg);
    attn_kernel<<<1024, 64, 0, stream>>>(meta, qb, kt, vb, bg, mwv);
    out_kernel<<<256, 256, 0, stream>>>(meta, mwv, Wo, bo, out);
}